// Round 13
// baseline (144.520 us; speedup 1.0000x reference)
//
#include <hip/hip_runtime.h>

typedef _Float16 half8  __attribute__((ext_vector_type(8)));
typedef float    f32x4  __attribute__((ext_vector_type(4)));
typedef float    f32x16 __attribute__((ext_vector_type(16)));

#define T_TOK 16384
#define D_DIM 4096
#define E_EXP 128
#define CAP   256
#define BM    64
#define NT    32   // macro K-steps per pipe, BK=64 each (K per pipe = 2048)

// A LDS: [pipe][buf][row 0..63][256 B]. Per row: h plane 128 B | m plane 128 B.
// Each plane = 8 chunks of 16 B (8 halfs: k = c*8..+8 of the 64-K step),
// stored at chunk c' = c ^ (row&7). Row stride 256 B == 0 mod 32 banks ->
// bank set depends only on chunk: every 8-lane phase of ds_write_b128 staging
// and ds_read_b128 fragment reads covers 8 distinct chunks = all 32 banks.
#define A_BUF  16384
#define A_PIPE 32768
#define SMEM   65536

// ---------------------------------------------------------------------------
// Kernel 0: wg (fp32) -> K-substep-tiled split-fp16 planes, scaled by 64.
// Substep s (k=32) block: h plane 8192 B | m plane 8192 B; expert e at e*64 B.
// ---------------------------------------------------------------------------
__global__ __launch_bounds__(256) void prep_wt(
    const float* __restrict__ wg, _Float16* __restrict__ wt)
{
    const int t = blockIdx.x * 256 + threadIdx.x;  // 65536 threads
    const int c = t & 3;
    const int e = (t >> 2) & 127;
    const int s = t >> 9;

    const float* src = wg + (size_t)e * D_DIM + s * 32 + c * 8;
    const f32x4 v0 = *reinterpret_cast<const f32x4*>(src);
    const f32x4 v1 = *reinterpret_cast<const f32x4*>(src + 4);

    half8 h, m;
#pragma unroll
    for (int j = 0; j < 4; j++) {
        float sv = v0[j] * 64.0f;
        _Float16 hh = (_Float16)sv;
        h[j] = hh; m[j] = (_Float16)(sv - (float)hh);
        sv = v1[j] * 64.0f;
        hh = (_Float16)sv;
        h[4 + j] = hh; m[4 + j] = (_Float16)(sv - (float)hh);
    }
    _Float16* dst = wt + (size_t)s * 8192 + e * 32 + c * 8;
    *reinterpret_cast<half8*>(dst)        = h;
    *reinterpret_cast<half8*>(dst + 4096) = m;
}

// ---------------------------------------------------------------------------
// Kernel A: BM=64, 32x32x16-MFMA, dual-K-pipe GEMM + fused gate + histogram.
// 1024 thr = 16 waves = 2 K-pipes x 2 row-groups x 4 col-groups; grid 256.
// Min-max-pipe config: per-CU totals LDS-read 49K cy, B-L2 65K, A-HBM ~60K.
// Issue order per step (R11 discipline): B subs 1-3 first, then A(t+1) HBM
// loads, then compute (vmcnt waits only cover B), stage A, lgkm-only barrier.
// ---------------------------------------------------------------------------
__global__ __launch_bounds__(1024, 4) void gemm_gate(
    const float* __restrict__ x, const _Float16* __restrict__ wt,
    float* __restrict__ out, float* __restrict__ me, int* __restrict__ cnt1)
{
    __shared__ char smem[SMEM];   // A tiles; logits+scratch alias after loop

    const int tid  = threadIdx.x;
    const int row0 = blockIdx.x * BM;
    const int lane = tid & 63;
    const int w    = tid >> 6;
    const int kp   = w >> 3;         // K-pipe 0/1
    const int rg   = (w >> 2) & 1;   // row-group: rows rg*32..+32
    const int cg   = w & 3;          // col-group: experts cg*32..+32
    const int col  = lane & 31;      // row (A,C) / expert (B) within tile
    const int k8   = lane >> 5;      // k-span: halfs k8*8..+8 per 16-K sub

    // ---- A staging role: threads 0-511 stage pipe 0, 512-1023 pipe 1 ----
    const int sp = tid >> 9;
    const int sr = (tid >> 3) & 63;
    const int sg = tid & 7;
    const float* xA = x + (size_t)(row0 + sr) * D_DIM + sp * 2048 + sg * 8;
    const int awr_h = sp * A_PIPE + sr * 256 + ((sg ^ (sr & 7)) * 16);
    // m plane at +128; + buf*A_BUF

    // ---- A fragment read base: row = rg*32 + col ----
    const char* const ard = smem + kp * A_PIPE + (rg * 32 + col) * 256;
    const int rsw = col & 7;
    // sub k: chunk c = k*2 + k8, swizzled c^rsw; m at +128

    // ---- B pointer: wt substep s32 = kp*64 + 2t + (k>>1); +16 halfs if k&1 --
    const _Float16* const wtB =
        wt + (size_t)(kp * 64) * 8192 + (cg * 32 + col) * 32 + k8 * 8;

    f32x16 acc = (f32x16)0.0f;

#define LOAD_BS(Bh, Bm, t, k)                                                 \
    {                                                                         \
        const _Float16* bp = wtB +                                            \
            (size_t)((2 * (t) + ((k) >> 1)) & 63) * 8192 + ((k) & 1) * 16;    \
        Bh = *reinterpret_cast<const half8*>(bp);                             \
        Bm = *reinterpret_cast<const half8*>(bp + 4096);                      \
    }

#define CONV_WRITE(a0, a1, buf)                                               \
    {                                                                         \
        half8 h, m;                                                           \
        _Pragma("unroll") for (int j = 0; j < 4; j++) {                       \
            _Float16 hh = (_Float16)a0[j];                                    \
            h[j] = hh; m[j] = (_Float16)(a0[j] - (float)hh);                  \
            hh = (_Float16)a1[j];                                             \
            h[4 + j] = hh; m[4 + j] = (_Float16)(a1[j] - (float)hh);          \
        }                                                                     \
        char* const wb = smem + (buf) * A_BUF + awr_h;                        \
        *reinterpret_cast<half8*>(wb)       = h;                              \
        *reinterpret_cast<half8*>(wb + 128) = m;                              \
    }

#define BAR()                                                                 \
    asm volatile("s_waitcnt lgkmcnt(0)" ::: "memory");                        \
    __builtin_amdgcn_sched_barrier(0);                                        \
    __builtin_amdgcn_s_barrier();                                             \
    __builtin_amdgcn_sched_barrier(0);

#define SUB(cur, k, Bh, Bm)                                                   \
    {                                                                         \
        const char* ab = ard + (cur) * A_BUF + ((((k) * 2 + k8) ^ rsw) * 16); \
        const half8 Ah = *reinterpret_cast<const half8*>(ab);                 \
        const half8 Am = *reinterpret_cast<const half8*>(ab + 128);           \
        acc = __builtin_amdgcn_mfma_f32_32x32x16_f16(Am, Bh, acc, 0, 0, 0);   \
        acc = __builtin_amdgcn_mfma_f32_32x32x16_f16(Ah, Bm, acc, 0, 0, 0);   \
        acc = __builtin_amdgcn_mfma_f32_32x32x16_f16(Ah, Bh, acc, 0, 0, 0);   \
    }

// Macro-step t: B subs 1-3 issued first (oldest), then A(t+1) HBM load, then
// compute subs 0-3 (vmcnt waits only touch B), B0 for t+1 mid-step, stage A.
#define STEP(cur, t)                                                          \
    {                                                                         \
        LOAD_BS(B1h, B1m, t, 1);                                              \
        LOAD_BS(B2h, B2m, t, 2);                                              \
        LOAD_BS(B3h, B3m, t, 3);                                              \
        __builtin_amdgcn_sched_barrier(0);                                    \
        const int kn = (((t) + 1) & (NT - 1)) * 64;                           \
        const f32x4 a0 = *reinterpret_cast<const f32x4*>(xA + kn);            \
        const f32x4 a1 = *reinterpret_cast<const f32x4*>(xA + kn + 4);        \
        __builtin_amdgcn_sched_barrier(0);                                    \
        SUB(cur, 0, B0h, B0m);                                                \
        LOAD_BS(B0h, B0m, (t) + 1, 0);                                        \
        SUB(cur, 1, B1h, B1m);                                                \
        SUB(cur, 2, B2h, B2m);                                                \
        SUB(cur, 3, B3h, B3m);                                                \
        CONV_WRITE(a0, a1, (cur) ^ 1);                                        \
        BAR();                                                                \
    }

    half8 B0h, B0m, B1h, B1m, B2h, B2m, B3h, B3m;

    // ---- prologue: A(0) -> buf0; B(step0, sub0) -> B0 ----
    {
        const f32x4 a0 = *reinterpret_cast<const f32x4*>(xA);
        const f32x4 a1 = *reinterpret_cast<const f32x4*>(xA + 4);
        LOAD_BS(B0h, B0m, 0, 0);
        CONV_WRITE(a0, a1, 0);
        BAR();
    }

    // ---- main loop: 32 macro-steps, 2 per iteration (static indices) ----
    for (int t = 0; t < NT; t += 2) {
        STEP(0, t);
        STEP(1, t + 1);
    }

#undef STEP
#undef SUB
#undef BAR
#undef CONV_WRITE
#undef LOAD_BS

    // ---- merge K-pipes into lg (aliases A smem), scale by 1/64 ----
    // C/D layout (m74/m101, R12-verified): col = lane&31,
    // local row = (reg&3) + 8*(reg>>2) + 4*k8; global row += rg*32.
    float* lg = reinterpret_cast<float*>(smem);   // [64][129] = 33024 B
    if (kp == 1) {
#pragma unroll
        for (int reg = 0; reg < 16; reg++) {
            const int row = rg * 32 + (reg & 3) + 8 * (reg >> 2) + 4 * k8;
            lg[row * 129 + cg * 32 + col] = acc[reg] * 0.015625f;
        }
    }
    __syncthreads();
    if (kp == 0) {
#pragma unroll
        for (int reg = 0; reg < 16; reg++) {
            const int row = rg * 32 + (reg & 3) + 8 * (reg >> 2) + 4 * k8;
            lg[row * 129 + cg * 32 + col] += acc[reg] * 0.015625f;
        }
    }
    __syncthreads();

    // ---- gate epilogue ----
    float* sm1v  = reinterpret_cast<float*>(smem + 40960);  // [64]
    float* sinvv = reinterpret_cast<float*>(smem + 41472);  // [64]

    if (tid < BM) {
        const int r = tid;
        const int t = row0 + r;
        float m1 = -1e30f, m2 = -1e30f;
        int   i1 = 0, i2 = 0;
        for (int e = 0; e < E_EXP; e++) {
            const float v = lg[r * 129 + e];
            if (v > m1)      { m2 = m1; i2 = i1; m1 = v; i1 = e; }
            else if (v > m2) { m2 = v; i2 = e; }
        }
        float s = 0.0f;
        for (int e = 0; e < E_EXP; e++) s += __expf(lg[r * 129 + e] - m1);
        const float inv = 1.0f / s;

        out[3 + 0 * T_TOK + t] = (float)i1;
        out[3 + 1 * T_TOK + t] = (float)i2;
        out[3 + 4 * T_TOK + t] = inv;
        out[3 + 5 * T_TOK + t] = __expf(m2 - m1) * inv;
        atomicAdd(&cnt1[i1], 1);
        sm1v[r]  = m1;
        sinvv[r] = inv;
    }
    __syncthreads();

    // parallel exp rewrite: 1024 threads x 8 cells (64 rows x 128 experts)
    {
        const int r  = tid >> 4;          // 0..63
        const int e0 = (tid & 15) * 8;    // 0..120
        const float m1 = sm1v[r], inv = sinvv[r];
#pragma unroll
        for (int j = 0; j < 8; j++)
            lg[r * 129 + e0 + j] = __expf(lg[r * 129 + e0 + j] - m1) * inv;
    }
    __syncthreads();

    if (tid < E_EXP) {
        float s = 0.0f;
        for (int r = 0; r < BM; r++) s += lg[r * 129 + tid];
        atomicAdd(&me[tid], s);
    }
}

// ---------------------------------------------------------------------------
// Kernel B: per-expert rank. 256 blocks x 1024 thr: blocks 0-127 scan idx1;
// blocks 128-255 scan idx2 starting at base = cnt1[e] (from gemm histogram).
// ---------------------------------------------------------------------------
__global__ __launch_bounds__(1024) void rank_kernel(
    float* __restrict__ out, const int* __restrict__ cnt1)
{
    const int  e      = blockIdx.x & 127;
    const bool second = blockIdx.x >= 128;
    const int  tid    = threadIdx.x;
    const int  lane   = tid & 63;
    const int  w      = tid >> 6;   // 0..15

    __shared__ int wtot[16];

    const float* idxA = out + 3 + (second ? T_TOK : 0);
    float* loc = out + 3 + (second ? 3 * T_TOK : 2 * T_TOK);

    const unsigned long long below = (1ull << lane) - 1ull;
    int base = second ? cnt1[e] : 0;

    for (int t0 = 0; t0 < T_TOK; t0 += 1024) {
        const int t = t0 + tid;
        const int f = ((int)idxA[t] == e);
        const unsigned long long m = __ballot(f);
        const int pre = __popcll(m & below);
        const int tot = __popcll(m);
        if (lane == 0) wtot[w] = tot;
        __syncthreads();
        int off = 0, all = 0;
#pragma unroll
        for (int i = 0; i < 16; i++) {
            const int v = wtot[i];
            if (i < w) off += v;
            all += v;
        }
        if (f) {
            const int rank = base + off + pre;
            loc[t] = (rank < CAP) ? (float)rank : 0.0f;
        }
        base += all;
        __syncthreads();
    }
}

// ---------------------------------------------------------------------------
// Kernel C: l_aux = sum(me * min(cnt1,CAP)) * E/(T*T); plus constants.
// ---------------------------------------------------------------------------
__global__ __launch_bounds__(128) void finalize_kernel(
    const float* __restrict__ me, const int* __restrict__ cnt1,
    float* __restrict__ out)
{
    __shared__ float red[2];
    const int tid = threadIdx.x;
    const int c = cnt1[tid];
    float p = me[tid] * (float)((c < CAP) ? c : CAP);
#pragma unroll
    for (int o = 32; o > 0; o >>= 1) p += __shfl_down(p, o);
    if ((tid & 63) == 0) red[tid >> 6] = p;
    __syncthreads();
    if (tid == 0) {
        const float tot = red[0] + red[1];
        out[0] = tot * ((float)E_EXP / ((float)T_TOK * (float)T_TOK));
        out[1] = (float)CAP;
        out[2] = (float)E_EXP;
    }
}

extern "C" void kernel_launch(void* const* d_in, const int* in_sizes, int n_in,
                              void* d_out, int out_size, void* d_ws, size_t ws_size,
                              hipStream_t stream)
{
    const float* x  = (const float*)d_in[0];
    const float* wg = (const float*)d_in[1];
    float* out = (float*)d_out;

    float* me   = (float*)d_ws;                      // 128 floats
    int*   cnt1 = (int*)((char*)d_ws + 512);         // 128 ints
    _Float16* wt = (_Float16*)((char*)d_ws + 1024);  // 2 MB K-tiled planes

    hipMemsetAsync(d_ws, 0, 1024, stream);
    prep_wt<<<256, 256, 0, stream>>>(wg, wt);
    gemm_gate<<<T_TOK / BM, 1024, 0, stream>>>(x, wt, out, me, cnt1);
    rank_kernel<<<2 * E_EXP, 1024, 0, stream>>>(out, cnt1);
    finalize_kernel<<<1, 128, 0, stream>>>(me, cnt1, out);
}

// Round 15
// 129.061 us; speedup vs baseline: 1.1198x; 1.1198x over previous
//
#include <hip/hip_runtime.h>

typedef _Float16 half8 __attribute__((ext_vector_type(8)));
typedef float    f32x4 __attribute__((ext_vector_type(4)));
typedef float    f32x16 __attribute__((ext_vector_type(16)));

#define T_TOK 16384
#define D_DIM 4096
#define E_EXP 128
#define CAP   256
#define BM    64
#define NT    16   // macro K-steps per sub-pipe (BK=64; K-quarter = 1024)

// A LDS: [sub-pipe][buf][row 0..63][256 B]. Per row: h plane 128 B | m plane
// 128 B; 8 chunks of 16 B each, chunk c stored at c ^ (row&7). All write and
// read 8-lane phases cover 8 distinct chunks = 32 banks (R13-verified layout).
#define A_BUF 16384
#define A_SP  32768

// ---------------------------------------------------------------------------
// Kernel 0: wg (fp32) -> K-substep-tiled split-fp16 planes, scaled by 64.
// Substep s (k=32): h plane 8192 B | m plane 8192 B; expert e at e*64 B.
// ---------------------------------------------------------------------------
__global__ __launch_bounds__(256) void prep_wt(
    const float* __restrict__ wg, _Float16* __restrict__ wt)
{
    const int t = blockIdx.x * 256 + threadIdx.x;  // 65536 threads
    const int c = t & 3;
    const int e = (t >> 2) & 127;
    const int s = t >> 9;

    const float* src = wg + (size_t)e * D_DIM + s * 32 + c * 8;
    const f32x4 v0 = *reinterpret_cast<const f32x4*>(src);
    const f32x4 v1 = *reinterpret_cast<const f32x4*>(src + 4);

    half8 h, m;
#pragma unroll
    for (int j = 0; j < 4; j++) {
        float sv = v0[j] * 64.0f;
        _Float16 hh = (_Float16)sv;
        h[j] = hh; m[j] = (_Float16)(sv - (float)hh);
        sv = v1[j] * 64.0f;
        hh = (_Float16)sv;
        h[4 + j] = hh; m[4 + j] = (_Float16)(sv - (float)hh);
    }
    _Float16* dst = wt + (size_t)s * 8192 + e * 32 + c * 8;
    *reinterpret_cast<half8*>(dst)        = h;
    *reinterpret_cast<half8*>(dst + 4096) = m;
}

// ---------------------------------------------------------------------------
// Kernel A: partial-K MFMA GEMM. grid 512 = 256 tiles x 2 K-halves; 512 thr
// = 8 waves = 2 sub-pipes (K-quarters) x 4 col-groups -> 2 blocks/CU.
// Wave tile 64 rows x 32 experts (rf=2, two independent acc chains).
// R15 FIX: sub-pipes are MERGED IN LDS before the lgw store (R14 raced:
// both sub-pipes plain-stored to the same lgw address, losing a K-quarter).
// ---------------------------------------------------------------------------
__global__ __launch_bounds__(512, 4) void gemm_partial(
    const float* __restrict__ x, const _Float16* __restrict__ wt,
    float* __restrict__ lgw)
{
    __shared__ char smem[2 * A_SP];   // 64 KB

    const int tid  = threadIdx.x;
    const int tile = blockIdx.x & 255;
    const int kh   = blockIdx.x >> 8;      // K-half 0/1
    const int row0 = tile * BM;
    const int lane = tid & 63;
    const int w    = tid >> 6;
    const int spw  = w >> 2;               // sub-pipe (K-quarter) 0/1
    const int cg   = w & 3;                // col-group: experts cg*32..+32
    const int col  = lane & 31;            // row (A,C) / expert (B)
    const int k8   = lane >> 5;            // k-span: halfs k8*8..+8 per 16-K

    // ---- A staging: threads 0-255 stage sp0, 256-511 sp1; 16 floats each --
    const int sp = tid >> 8;
    const int ro = tid & 255;
    const int sr = ro >> 2;
    const int sg = ro & 3;
    const float* xA = x + (size_t)(row0 + sr) * D_DIM +
                      kh * 2048 + sp * 1024 + sg * 16;
    const int aw  = sp * A_SP + sr * 256;
    const int c0  = ((sg * 2    ) ^ (sr & 7)) * 16;
    const int c1  = ((sg * 2 + 1) ^ (sr & 7)) * 16;

    // ---- A fragment read base ----
    const char* const ard = smem + spw * A_SP + col * 256;  // + rf*8192
    const int rsw = col & 7;

    // ---- B base: global substep s32 = kh*64 + spw*32 + 2t + (k>>1) ----
    const _Float16* const wtB =
        wt + (size_t)(kh * 64 + spw * 32) * 8192 + (cg * 32 + col) * 32 + k8 * 8;

    f32x16 acc0 = (f32x16)0.0f, acc1 = (f32x16)0.0f;

#define LOAD_BS(Bh, Bm, t, k)                                                 \
    {                                                                         \
        const _Float16* bp = wtB +                                            \
            (size_t)((2 * (t) + ((k) >> 1)) & 31) * 8192 + ((k) & 1) * 16;    \
        Bh = *reinterpret_cast<const half8*>(bp);                             \
        Bm = *reinterpret_cast<const half8*>(bp + 4096);                      \
    }

#define CONV_WRITE(a0v, a1v, a2v, a3v, buf)                                   \
    {                                                                         \
        half8 h0, m0, h1, m1;                                                 \
        _Pragma("unroll") for (int j = 0; j < 4; j++) {                       \
            _Float16 hh = (_Float16)a0v[j];                                   \
            h0[j] = hh; m0[j] = (_Float16)(a0v[j] - (float)hh);               \
            hh = (_Float16)a1v[j];                                            \
            h0[4 + j] = hh; m0[4 + j] = (_Float16)(a1v[j] - (float)hh);       \
            hh = (_Float16)a2v[j];                                            \
            h1[j] = hh; m1[j] = (_Float16)(a2v[j] - (float)hh);               \
            hh = (_Float16)a3v[j];                                            \
            h1[4 + j] = hh; m1[4 + j] = (_Float16)(a3v[j] - (float)hh);       \
        }                                                                     \
        char* const wb = smem + aw + (buf) * A_BUF;                           \
        *reinterpret_cast<half8*>(wb + c0)       = h0;                        \
        *reinterpret_cast<half8*>(wb + c1)       = h1;                        \
        *reinterpret_cast<half8*>(wb + c0 + 128) = m0;                        \
        *reinterpret_cast<half8*>(wb + c1 + 128) = m1;                        \
    }

#define BAR()                                                                 \
    asm volatile("s_waitcnt lgkmcnt(0)" ::: "memory");                        \
    __builtin_amdgcn_sched_barrier(0);                                        \
    __builtin_amdgcn_s_barrier();                                             \
    __builtin_amdgcn_sched_barrier(0);

#define SUB(cur, k, Bh, Bm)                                                   \
    {                                                                         \
        const int ch = ((((k) * 2 + k8) ^ rsw) * 16);                         \
        const char* ab0 = ard + (cur) * A_BUF + ch;                           \
        const char* ab1 = ab0 + 32 * 256;                                     \
        const half8 Ah0 = *reinterpret_cast<const half8*>(ab0);               \
        const half8 Am0 = *reinterpret_cast<const half8*>(ab0 + 128);         \
        const half8 Ah1 = *reinterpret_cast<const half8*>(ab1);               \
        const half8 Am1 = *reinterpret_cast<const half8*>(ab1 + 128);         \
        acc0 = __builtin_amdgcn_mfma_f32_32x32x16_f16(Am0, Bh, acc0, 0,0,0);  \
        acc1 = __builtin_amdgcn_mfma_f32_32x32x16_f16(Am1, Bh, acc1, 0,0,0);  \
        acc0 = __builtin_amdgcn_mfma_f32_32x32x16_f16(Ah0, Bm, acc0, 0,0,0);  \
        acc1 = __builtin_amdgcn_mfma_f32_32x32x16_f16(Ah1, Bm, acc1, 0,0,0);  \
        acc0 = __builtin_amdgcn_mfma_f32_32x32x16_f16(Ah0, Bh, acc0, 0,0,0);  \
        acc1 = __builtin_amdgcn_mfma_f32_32x32x16_f16(Ah1, Bh, acc1, 0,0,0);  \
    }

// Macro-step t: B subs 1-3 first (oldest), then A(t+1) HBM loads, then
// compute subs 0-3 (vmcnt waits only touch B), B0 for t+1 mid-step,
// stage A(t+1), lgkm-only barrier.
#define STEP(cur, t)                                                          \
    {                                                                         \
        LOAD_BS(B1h, B1m, t, 1);                                              \
        LOAD_BS(B2h, B2m, t, 2);                                              \
        LOAD_BS(B3h, B3m, t, 3);                                              \
        __builtin_amdgcn_sched_barrier(0);                                    \
        const int kn = (((t) + 1) & (NT - 1)) * 64;                           \
        const f32x4 av0 = *reinterpret_cast<const f32x4*>(xA + kn);           \
        const f32x4 av1 = *reinterpret_cast<const f32x4*>(xA + kn + 4);       \
        const f32x4 av2 = *reinterpret_cast<const f32x4*>(xA + kn + 8);       \
        const f32x4 av3 = *reinterpret_cast<const f32x4*>(xA + kn + 12);      \
        __builtin_amdgcn_sched_barrier(0);                                    \
        SUB(cur, 0, B0h, B0m);                                                \
        LOAD_BS(B0h, B0m, (t) + 1, 0);                                        \
        SUB(cur, 1, B1h, B1m);                                                \
        SUB(cur, 2, B2h, B2m);                                                \
        SUB(cur, 3, B3h, B3m);                                                \
        CONV_WRITE(av0, av1, av2, av3, (cur) ^ 1);                            \
        BAR();                                                                \
    }

    half8 B0h, B0m, B1h, B1m, B2h, B2m, B3h, B3m;

    // ---- prologue: A(0) -> buf0; B(0,sub0) -> B0 ----
    {
        const f32x4 a0 = *reinterpret_cast<const f32x4*>(xA);
        const f32x4 a1 = *reinterpret_cast<const f32x4*>(xA + 4);
        const f32x4 a2 = *reinterpret_cast<const f32x4*>(xA + 8);
        const f32x4 a3 = *reinterpret_cast<const f32x4*>(xA + 12);
        LOAD_BS(B0h, B0m, 0, 0);
        CONV_WRITE(a0, a1, a2, a3, 0);
        BAR();
    }

    // ---- main loop: 16 macro-steps, 2 per iteration (static indices) ----
    for (int t = 0; t < NT; t += 2) {
        STEP(0, t);
        STEP(1, t + 1);
    }

#undef STEP
#undef SUB
#undef BAR
#undef CONV_WRITE
#undef LOAD_BS

    // ---- merge the two sub-pipes IN LDS (R15 fix), store to lgw[kh] ----
    // C/D layout (R12/R13-verified): col = lane&31,
    // row = rf*32 + (reg&3) + 8*(reg>>2) + 4*k8.
    float* mg = reinterpret_cast<float*>(smem);   // [64][128] = 32 KB
    __syncthreads();   // all waves past the K loop; A buffers are dead
    if (spw == 1) {
        float* b = mg + cg * 32 + col;
#pragma unroll
        for (int reg = 0; reg < 16; reg++) {
            const int row = (reg & 3) + 8 * (reg >> 2) + 4 * k8;
            b[row * 128]        = acc0[reg];
            b[(row + 32) * 128] = acc1[reg];
        }
    }
    __syncthreads();
    if (spw == 0) {
        float* dst = lgw + ((size_t)kh * 256 + tile) * 8192 + cg * 32 + col;
        const float* srcp = mg + cg * 32 + col;
#pragma unroll
        for (int reg = 0; reg < 16; reg++) {
            const int row = (reg & 3) + 8 * (reg >> 2) + 4 * k8;
            dst[row * 128]        = acc0[reg] + srcp[row * 128];
            dst[(row + 32) * 128] = acc1[reg] + srcp[(row + 32) * 128];
        }
    }
}

// ---------------------------------------------------------------------------
// Kernel G: sum the two K-half partials, scale by 1/64, top2 + softmax,
// write idx/gates, idx1 histogram, me partial sums. 256 blocks x 256 thr.
// ---------------------------------------------------------------------------
__global__ __launch_bounds__(256) void gate_kernel(
    const float* __restrict__ lgw, float* __restrict__ out,
    float* __restrict__ me, int* __restrict__ cnt1)
{
    __shared__ float lg[BM * 129];
    __shared__ float sm1v[BM], sinvv[BM];

    const int tile = blockIdx.x;
    const int tid  = threadIdx.x;
    const int row0 = tile * BM;

    const float* p0 = lgw + (size_t)tile * 8192;
    const float* p1 = p0 + (size_t)256 * 8192;

#pragma unroll
    for (int i = 0; i < 8; i++) {
        const int off = i * 1024 + tid * 4;
        const f32x4 v0 = *reinterpret_cast<const f32x4*>(p0 + off);
        const f32x4 v1 = *reinterpret_cast<const f32x4*>(p1 + off);
        const int r = off >> 7, c = off & 127;
#pragma unroll
        for (int j = 0; j < 4; j++)
            lg[r * 129 + c + j] = (v0[j] + v1[j]) * 0.015625f;
    }
    __syncthreads();

    if (tid < BM) {
        const int r = tid;
        const int t = row0 + r;
        float m1 = -1e30f, m2 = -1e30f;
        int   i1 = 0, i2 = 0;
        for (int e = 0; e < E_EXP; e++) {
            const float v = lg[r * 129 + e];
            if (v > m1)      { m2 = m1; i2 = i1; m1 = v; i1 = e; }
            else if (v > m2) { m2 = v; i2 = e; }
        }
        float s = 0.0f;
        for (int e = 0; e < E_EXP; e++) s += __expf(lg[r * 129 + e] - m1);
        const float inv = 1.0f / s;

        out[3 + 0 * T_TOK + t] = (float)i1;
        out[3 + 1 * T_TOK + t] = (float)i2;
        out[3 + 4 * T_TOK + t] = inv;
        out[3 + 5 * T_TOK + t] = __expf(m2 - m1) * inv;
        atomicAdd(&cnt1[i1], 1);
        sm1v[r]  = m1;
        sinvv[r] = inv;
    }
    __syncthreads();

    // parallel exp rewrite: 256 thr x 32 cells
    {
        const int r  = tid >> 2;
        const int e0 = (tid & 3) * 32;
        const float m1 = sm1v[r], inv = sinvv[r];
#pragma unroll
        for (int j = 0; j < 32; j++)
            lg[r * 129 + e0 + j] = __expf(lg[r * 129 + e0 + j] - m1) * inv;
    }
    __syncthreads();

    if (tid < E_EXP) {
        float s = 0.0f;
        for (int r = 0; r < BM; r++) s += lg[r * 129 + tid];
        atomicAdd(&me[tid], s);
    }
}

// ---------------------------------------------------------------------------
// Kernel B: per-expert rank. 256 blocks x 1024 thr: blocks 0-127 scan idx1;
// blocks 128-255 scan idx2 starting at base = cnt1[e] (from gate histogram).
// ---------------------------------------------------------------------------
__global__ __launch_bounds__(1024) void rank_kernel(
    float* __restrict__ out, const int* __restrict__ cnt1)
{
    const int  e      = blockIdx.x & 127;
    const bool second = blockIdx.x >= 128;
    const int  tid    = threadIdx.x;
    const int  lane   = tid & 63;
    const int  w      = tid >> 6;   // 0..15

    __shared__ int wtot[16];

    const float* idxA = out + 3 + (second ? T_TOK : 0);
    float* loc = out + 3 + (second ? 3 * T_TOK : 2 * T_TOK);

    const unsigned long long below = (1ull << lane) - 1ull;
    int base = second ? cnt1[e] : 0;

    for (int t0 = 0; t0 < T_TOK; t0 += 1024) {
        const int t = t0 + tid;
        const int f = ((int)idxA[t] == e);
        const unsigned long long m = __ballot(f);
        const int pre = __popcll(m & below);
        const int tot = __popcll(m);
        if (lane == 0) wtot[w] = tot;
        __syncthreads();
        int off = 0, all = 0;
#pragma unroll
        for (int i = 0; i < 16; i++) {
            const int v = wtot[i];
            if (i < w) off += v;
            all += v;
        }
        if (f) {
            const int rank = base + off + pre;
            loc[t] = (rank < CAP) ? (float)rank : 0.0f;
        }
        base += all;
        __syncthreads();
    }
}

// ---------------------------------------------------------------------------
// Kernel C: l_aux = sum(me * min(cnt1,CAP)) * E/(T*T); plus constants.
// ---------------------------------------------------------------------------
__global__ __launch_bounds__(128) void finalize_kernel(
    const float* __restrict__ me, const int* __restrict__ cnt1,
    float* __restrict__ out)
{
    __shared__ float red[2];
    const int tid = threadIdx.x;
    const int c = cnt1[tid];
    float p = me[tid] * (float)((c < CAP) ? c : CAP);
#pragma unroll
    for (int o = 32; o > 0; o >>= 1) p += __shfl_down(p, o);
    if ((tid & 63) == 0) red[tid >> 6] = p;
    __syncthreads();
    if (tid == 0) {
        const float tot = red[0] + red[1];
        out[0] = tot * ((float)E_EXP / ((float)T_TOK * (float)T_TOK));
        out[1] = (float)CAP;
        out[2] = (float)E_EXP;
    }
}

extern "C" void kernel_launch(void* const* d_in, const int* in_sizes, int n_in,
                              void* d_out, int out_size, void* d_ws, size_t ws_size,
                              hipStream_t stream)
{
    const float* x  = (const float*)d_in[0];
    const float* wg = (const float*)d_in[1];
    float* out = (float*)d_out;

    float* me   = (float*)d_ws;                          // 128 floats
    int*   cnt1 = (int*)((char*)d_ws + 512);             // 128 ints
    _Float16* wt = (_Float16*)((char*)d_ws + 1024);      // 2 MB tiled planes
    float* lgw  = (float*)((char*)d_ws + 1024 + (size_t)2 * 1024 * 1024); // 16 MB

    hipMemsetAsync(d_ws, 0, 1024, stream);
    prep_wt<<<256, 256, 0, stream>>>(wg, wt);
    gemm_partial<<<512, 512, 0, stream>>>(x, wt, lgw);
    gate_kernel<<<256, 256, 0, stream>>>(lgw, out, me, cnt1);
    rank_kernel<<<2 * E_EXP, 1024, 0, stream>>>(out, cnt1);
    finalize_kernel<<<1, 128, 0, stream>>>(me, cnt1, out);
}

// Round 16
// 113.846 us; speedup vs baseline: 1.2694x; 1.1336x over previous
//
#include <hip/hip_runtime.h>

typedef _Float16 half8 __attribute__((ext_vector_type(8)));
typedef _Float16 half4 __attribute__((ext_vector_type(4)));
typedef float    f32x4 __attribute__((ext_vector_type(4)));

#define T_TOK 16384
#define D_DIM 4096
#define E_EXP 128
#define CAP   256
#define BM    64
#define NT    32   // macro K-steps per pipe, BK=64 each (K per pipe = 2048)

// A LDS: [pipe][buf][row 0..63][256 B]. Per row: 2 ks-blocks of 128 B (k=32).
// Within each 128B block: 8 chunks of 16B; h at chunk (g ^ (row&7)), m at
// ((g|4) ^ (row&7)), g = k-group 0..3. Write phases 2-way aliased (free),
// read phases conflict-free (R10/R11-verified layout).
#define A_BUF_SZ  16384
#define A_PIPE_SZ 32768

// ---------------------------------------------------------------------------
// Kernel 0: wg (fp32) -> K-step-tiled split-fp16 planes, scaled by 64.
// Substep s (k=32) block: h plane 8192 B | m plane 8192 B; expert e at e*64 B.
// ---------------------------------------------------------------------------
__global__ __launch_bounds__(256) void prep_wt(
    const float* __restrict__ wg, _Float16* __restrict__ wt)
{
    const int t = blockIdx.x * 256 + threadIdx.x;  // 65536 threads
    const int c = t & 3;
    const int e = (t >> 2) & 127;
    const int s = t >> 9;

    const float* src = wg + (size_t)e * D_DIM + s * 32 + c * 8;
    const f32x4 v0 = *reinterpret_cast<const f32x4*>(src);
    const f32x4 v1 = *reinterpret_cast<const f32x4*>(src + 4);

    half8 h, m;
#pragma unroll
    for (int j = 0; j < 4; j++) {
        float sv = v0[j] * 64.0f;
        _Float16 hh = (_Float16)sv;
        h[j] = hh; m[j] = (_Float16)(sv - (float)hh);
        sv = v1[j] * 64.0f;
        hh = (_Float16)sv;
        h[4 + j] = hh; m[4 + j] = (_Float16)(sv - (float)hh);
    }
    _Float16* dst = wt + (size_t)s * 8192 + e * 32 + c * 8;
    *reinterpret_cast<half8*>(dst)        = h;
    *reinterpret_cast<half8*>(dst + 4096) = m;
}

// ---------------------------------------------------------------------------
// Kernel A (R11, best-measured): BM=64 dual-K-pipe MFMA GEMM + fused gate
// epilogue + idx1 histogram. 1024 thr = 16 waves = 2 K-pipes x 8 expert-
// groups (16 experts each). Issue order per step: B(t) L2-loads FIRST, then
// A(t+2) HBM-loads, then MFMAs (vmcnt waits touch only B), then CONV_WRITE
// of A(t+1) (landed a full step ago), then lgkm-only barrier.
// R16 delta: parallel exp rewrite in the epilogue (R13-verified pattern).
// ---------------------------------------------------------------------------
__global__ __launch_bounds__(1024, 4) void gemm_gate(
    const float* __restrict__ x, const _Float16* __restrict__ wt,
    float* __restrict__ out, float* __restrict__ me, int* __restrict__ cnt1)
{
    __shared__ char smem[2 * A_PIPE_SZ];   // 64 KB A tiles; logits alias after

    const int tid  = threadIdx.x;
    const int row0 = blockIdx.x * BM;
    const int lane = tid & 63;
    const int w    = tid >> 6;
    const int kp   = w >> 3;     // K-pipe 0/1
    const int wl   = w & 7;      // expert group: experts wl*16 .. +16
    const int lr   = lane & 15;
    const int lq   = lane >> 4;

    // ---- A staging role: threads 0-511 stage pipe 0, 512-1023 pipe 1 ----
    const int sp   = tid >> 9;
    const int srow = (tid >> 3) & 63;
    const int sg   = tid & 7;
    const float* xA = x + (size_t)(row0 + srow) * D_DIM + sp * 2048 + sg * 8;
    const int awr_h = sp * A_PIPE_SZ + srow * 256 + (sg >> 2) * 128 +
                      (((sg & 3)    ) ^ (srow & 7)) * 16;
    const int awr_m = sp * A_PIPE_SZ + srow * 256 + (sg >> 2) * 128 +
                      (((sg & 3) | 4) ^ (srow & 7)) * 16;

    // ---- A fragment read offsets (pipe kp) ----
    const int ah_ch = ((lq    ) ^ (lr & 7)) * 16;
    const int am_ch = ((lq | 4) ^ (lr & 7)) * 16;
    const char* const ard = smem + kp * A_PIPE_SZ;

    // ---- B fragment base: global substep s = kp*64 + 2t + ks ----
    const _Float16* const wtB =
        wt + (size_t)(kp * 64) * 8192 + (wl * 16 + lr) * 32 + lq * 8;

    f32x4 acc[4];
#pragma unroll
    for (int i = 0; i < 4; i++) acc[i] = (f32x4)0.0f;

#define CONV_WRITE(a0, a1, buf)                                               \
    {                                                                         \
        half8 h, m;                                                           \
        _Pragma("unroll") for (int j = 0; j < 4; j++) {                       \
            _Float16 hh = (_Float16)a0[j];                                    \
            h[j] = hh; m[j] = (_Float16)(a0[j] - (float)hh);                  \
            hh = (_Float16)a1[j];                                             \
            h[4 + j] = hh; m[4 + j] = (_Float16)(a1[j] - (float)hh);          \
        }                                                                     \
        char* const wb = smem + (buf) * A_BUF_SZ;                             \
        *reinterpret_cast<half8*>(wb + awr_h) = h;                            \
        *reinterpret_cast<half8*>(wb + awr_m) = m;                            \
    }

#define BAR()                                                                 \
    asm volatile("s_waitcnt lgkmcnt(0)" ::: "memory");                        \
    __builtin_amdgcn_sched_barrier(0);                                        \
    __builtin_amdgcn_s_barrier();                                             \
    __builtin_amdgcn_sched_barrier(0);

#define SUBSTEP(cur, ks, Bh, Bm)                                              \
    {                                                                         \
        half8 Ah[4], Am[4];                                                   \
        _Pragma("unroll") for (int rf = 0; rf < 4; rf++) {                    \
            const char* ab = ard + (cur) * A_BUF_SZ +                         \
                             (rf * 16 + lr) * 256 + (ks) * 128;               \
            Ah[rf] = *reinterpret_cast<const half8*>(ab + ah_ch);             \
            Am[rf] = *reinterpret_cast<const half8*>(ab + am_ch);             \
        }                                                                     \
        _Pragma("unroll") for (int rf = 0; rf < 4; rf++) {                    \
            acc[rf] = __builtin_amdgcn_mfma_f32_16x16x32_f16(                 \
                Am[rf], Bh, acc[rf], 0, 0, 0);                                \
            acc[rf] = __builtin_amdgcn_mfma_f32_16x16x32_f16(                 \
                Ah[rf], Bm, acc[rf], 0, 0, 0);                                \
            acc[rf] = __builtin_amdgcn_mfma_f32_16x16x32_f16(                 \
                Ah[rf], Bh, acc[rf], 0, 0, 0);                                \
        }                                                                     \
    }

// Macro-step t. AC holds A(t+1) (loaded last step); AN receives A(t+2).
// B first (oldest), A after: MFMA vmcnt waits never include an HBM load.
#define STEP(cur, t, AC0, AC1, AN0, AN1)                                      \
    {                                                                         \
        const _Float16* bp0 = wtB + (size_t)((2 * (t)    ) & 63) * 8192;      \
        const _Float16* bp1 = wtB + (size_t)((2 * (t) + 1) & 63) * 8192;      \
        const half8 Bh0 = *reinterpret_cast<const half8*>(bp0);               \
        const half8 Bm0 = *reinterpret_cast<const half8*>(bp0 + 4096);        \
        const half8 Bh1 = *reinterpret_cast<const half8*>(bp1);               \
        const half8 Bm1 = *reinterpret_cast<const half8*>(bp1 + 4096);        \
        __builtin_amdgcn_sched_barrier(0);                                    \
        const int kn = (((t) + 2) & (NT - 1)) * 64;                           \
        AN0 = *reinterpret_cast<const f32x4*>(xA + kn);                       \
        AN1 = *reinterpret_cast<const f32x4*>(xA + kn + 4);                   \
        __builtin_amdgcn_sched_barrier(0);                                    \
        SUBSTEP(cur, 0, Bh0, Bm0);                                            \
        SUBSTEP(cur, 1, Bh1, Bm1);                                            \
        CONV_WRITE(AC0, AC1, (cur) ^ 1);                                      \
        BAR();                                                                \
    }

    f32x4 aA0, aA1, aB0, aB1;

    // ---- prologue: A(0) -> buf0; A(1) -> regs ----
    {
        const f32x4 a00 = *reinterpret_cast<const f32x4*>(xA);
        const f32x4 a01 = *reinterpret_cast<const f32x4*>(xA + 4);
        aA0 = *reinterpret_cast<const f32x4*>(xA + 64);
        aA1 = *reinterpret_cast<const f32x4*>(xA + 68);
        CONV_WRITE(a00, a01, 0);
        BAR();
    }

    // ---- main loop: 32 macro-steps, 2 per iteration (static indices) ----
    for (int t = 0; t < NT; t += 2) {
        STEP(0, t,     aA0, aA1, aB0, aB1);
        STEP(1, t + 1, aB0, aB1, aA0, aA1);
    }

#undef STEP
#undef SUBSTEP
#undef BAR
#undef CONV_WRITE

    // ---- merge the two K-pipes into lg (aliases A smem), scale by 1/64 ----
    float* lg = reinterpret_cast<float*>(smem);   // [64][129] = 33 KB
    if (kp == 1) {
#pragma unroll
        for (int rf = 0; rf < 4; rf++)
#pragma unroll
            for (int r = 0; r < 4; r++)
                lg[(rf * 16 + lq * 4 + r) * 129 + wl * 16 + lr] =
                    acc[rf][r] * 0.015625f;
    }
    __syncthreads();
    if (kp == 0) {
#pragma unroll
        for (int rf = 0; rf < 4; rf++)
#pragma unroll
            for (int r = 0; r < 4; r++)
                lg[(rf * 16 + lq * 4 + r) * 129 + wl * 16 + lr] +=
                    acc[rf][r] * 0.015625f;
    }
    __syncthreads();

    // ---- gate epilogue ----
    float* sm1v  = reinterpret_cast<float*>(smem + 40960);  // [64]
    float* sinvv = reinterpret_cast<float*>(smem + 41472);  // [64]

    if (tid < BM) {
        const int r = tid;
        const int t = row0 + r;
        float m1 = -1e30f, m2 = -1e30f;
        int   i1 = 0, i2 = 0;
        for (int e = 0; e < E_EXP; e++) {
            const float v = lg[r * 129 + e];
            if (v > m1)      { m2 = m1; i2 = i1; m1 = v; i1 = e; }
            else if (v > m2) { m2 = v; i2 = e; }
        }
        float s = 0.0f;
        for (int e = 0; e < E_EXP; e++) s += __expf(lg[r * 129 + e] - m1);
        const float inv = 1.0f / s;

        out[3 + 0 * T_TOK + t] = (float)i1;
        out[3 + 1 * T_TOK + t] = (float)i2;
        out[3 + 4 * T_TOK + t] = inv;
        out[3 + 5 * T_TOK + t] = __expf(m2 - m1) * inv;
        atomicAdd(&cnt1[i1], 1);
        sm1v[r]  = m1;
        sinvv[r] = inv;
    }
    __syncthreads();

    // parallel exp rewrite: 1024 threads x 8 cells (64 rows x 128 experts)
    {
        const int r  = tid >> 4;          // 0..63
        const int e0 = (tid & 15) * 8;    // 0..120
        const float m1 = sm1v[r], inv = sinvv[r];
#pragma unroll
        for (int j = 0; j < 8; j++)
            lg[r * 129 + e0 + j] = __expf(lg[r * 129 + e0 + j] - m1) * inv;
    }
    __syncthreads();

    if (tid < E_EXP) {
        float s = 0.0f;
        for (int r = 0; r < BM; r++) s += lg[r * 129 + tid];
        atomicAdd(&me[tid], s);
    }
}

// ---------------------------------------------------------------------------
// Kernel B: per-expert rank. 256 blocks x 1024 thr: blocks 0-127 scan idx1;
// blocks 128-255 scan idx2 starting at base = cnt1[e] (from gemm histogram).
// ---------------------------------------------------------------------------
__global__ __launch_bounds__(1024) void rank_kernel(
    float* __restrict__ out, const int* __restrict__ cnt1)
{
    const int  e      = blockIdx.x & 127;
    const bool second = blockIdx.x >= 128;
    const int  tid    = threadIdx.x;
    const int  lane   = tid & 63;
    const int  w      = tid >> 6;   // 0..15

    __shared__ int wtot[16];

    const float* idxA = out + 3 + (second ? T_TOK : 0);
    float* loc = out + 3 + (second ? 3 * T_TOK : 2 * T_TOK);

    const unsigned long long below = (1ull << lane) - 1ull;
    int base = second ? cnt1[e] : 0;

    for (int t0 = 0; t0 < T_TOK; t0 += 1024) {
        const int t = t0 + tid;
        const int f = ((int)idxA[t] == e);
        const unsigned long long m = __ballot(f);
        const int pre = __popcll(m & below);
        const int tot = __popcll(m);
        if (lane == 0) wtot[w] = tot;
        __syncthreads();
        int off = 0, all = 0;
#pragma unroll
        for (int i = 0; i < 16; i++) {
            const int v = wtot[i];
            if (i < w) off += v;
            all += v;
        }
        if (f) {
            const int rank = base + off + pre;
            loc[t] = (rank < CAP) ? (float)rank : 0.0f;
        }
        base += all;
        __syncthreads();
    }
}

// ---------------------------------------------------------------------------
// Kernel C: l_aux = sum(me * min(cnt1,CAP)) * E/(T*T); plus constants.
// ---------------------------------------------------------------------------
__global__ __launch_bounds__(128) void finalize_kernel(
    const float* __restrict__ me, const int* __restrict__ cnt1,
    float* __restrict__ out)
{
    __shared__ float red[2];
    const int tid = threadIdx.x;
    const int c = cnt1[tid];
    float p = me[tid] * (float)((c < CAP) ? c : CAP);
#pragma unroll
    for (int o = 32; o > 0; o >>= 1) p += __shfl_down(p, o);
    if ((tid & 63) == 0) red[tid >> 6] = p;
    __syncthreads();
    if (tid == 0) {
        const float tot = red[0] + red[1];
        out[0] = tot * ((float)E_EXP / ((float)T_TOK * (float)T_TOK));
        out[1] = (float)CAP;
        out[2] = (float)E_EXP;
    }
}

extern "C" void kernel_launch(void* const* d_in, const int* in_sizes, int n_in,
                              void* d_out, int out_size, void* d_ws, size_t ws_size,
                              hipStream_t stream)
{
    const float* x  = (const float*)d_in[0];
    const float* wg = (const float*)d_in[1];
    float* out = (float*)d_out;

    float* me   = (float*)d_ws;                      // 128 floats
    int*   cnt1 = (int*)((char*)d_ws + 512);         // 128 ints
    _Float16* wt = (_Float16*)((char*)d_ws + 1024);  // 2 MB K-tiled planes

    hipMemsetAsync(d_ws, 0, 1024, stream);
    prep_wt<<<256, 256, 0, stream>>>(wg, wt);
    gemm_gate<<<T_TOK / BM, 1024, 0, stream>>>(x, wt, out, me, cnt1);
    rank_kernel<<<2 * E_EXP, 1024, 0, stream>>>(out, cnt1);
    finalize_kernel<<<1, 128, 0, stream>>>(me, cnt1, out);
}

// Round 17
// 105.039 us; speedup vs baseline: 1.3759x; 1.0838x over previous
//
#include <hip/hip_runtime.h>

typedef _Float16 half8 __attribute__((ext_vector_type(8)));
typedef _Float16 half4 __attribute__((ext_vector_type(4)));
typedef float    f32x4 __attribute__((ext_vector_type(4)));

#define T_TOK 16384
#define D_DIM 4096
#define E_EXP 128
#define CAP   256
#define BM    64
#define NT    32   // macro K-steps per pipe, BK=64 each (K per pipe = 2048)

// A LDS: [pipe][buf][row 0..63][256 B]. Per row: 2 ks-blocks of 128 B (k=32).
// Within each 128B block: 8 chunks of 16B; h at chunk (g ^ (row&7)), m at
// ((g|4) ^ (row&7)), g = k-group 0..3. Write phases 2-way aliased (free),
// read phases conflict-free (R10/R11-verified layout).
#define A_BUF_SZ  16384
#define A_PIPE_SZ 32768

// ---------------------------------------------------------------------------
// Kernel 0: wg (fp32) -> K-step-tiled split-fp16 planes, scaled by 64.
// Substep s (k=32) block: h plane 8192 B | m plane 8192 B; expert e at e*64 B.
// ---------------------------------------------------------------------------
__global__ __launch_bounds__(256) void prep_wt(
    const float* __restrict__ wg, _Float16* __restrict__ wt)
{
    const int t = blockIdx.x * 256 + threadIdx.x;  // 65536 threads
    const int c = t & 3;
    const int e = (t >> 2) & 127;
    const int s = t >> 9;

    const float* src = wg + (size_t)e * D_DIM + s * 32 + c * 8;
    const f32x4 v0 = *reinterpret_cast<const f32x4*>(src);
    const f32x4 v1 = *reinterpret_cast<const f32x4*>(src + 4);

    half8 h, m;
#pragma unroll
    for (int j = 0; j < 4; j++) {
        float sv = v0[j] * 64.0f;
        _Float16 hh = (_Float16)sv;
        h[j] = hh; m[j] = (_Float16)(sv - (float)hh);
        sv = v1[j] * 64.0f;
        hh = (_Float16)sv;
        h[4 + j] = hh; m[4 + j] = (_Float16)(sv - (float)hh);
    }
    _Float16* dst = wt + (size_t)s * 8192 + e * 32 + c * 8;
    *reinterpret_cast<half8*>(dst)        = h;
    *reinterpret_cast<half8*>(dst + 4096) = m;
}

// ---------------------------------------------------------------------------
// Kernel A: R16 base + ANTI-PHASE K-pipes. 1024 thr = 16 waves = 2 K-pipes
// x 8 expert-groups. Pipe 0 per step: B(t) loads -> A(t+2) loads -> MFMA ->
// stage A(t+1) -> lgkm-barrier. Pipe 1 per step: MFMA (B pre-loaded one step
// ahead, ping-pong P/Q) -> B(t+1) loads -> A(t+2) loads -> stage -> barrier.
// At any instant half the waves are in the LDS/MFMA phase while the other
// half drive TCP -> the two dominant pipes overlap instead of adding.
// Wave-uniform branch; both branches execute identical barrier counts.
// ---------------------------------------------------------------------------
__global__ __launch_bounds__(1024, 4) void gemm_gate(
    const float* __restrict__ x, const _Float16* __restrict__ wt,
    float* __restrict__ out, float* __restrict__ me, int* __restrict__ cnt1)
{
    __shared__ char smem[2 * A_PIPE_SZ];   // 64 KB A tiles; logits alias after

    const int tid  = threadIdx.x;
    const int row0 = blockIdx.x * BM;
    const int lane = tid & 63;
    const int w    = tid >> 6;
    const int kp   = w >> 3;     // K-pipe 0/1
    const int wl   = w & 7;      // expert group: experts wl*16 .. +16
    const int lr   = lane & 15;
    const int lq   = lane >> 4;

    // ---- A staging role: threads 0-511 stage pipe 0, 512-1023 pipe 1 ----
    const int sp   = tid >> 9;
    const int srow = (tid >> 3) & 63;
    const int sg   = tid & 7;
    const float* xA = x + (size_t)(row0 + srow) * D_DIM + sp * 2048 + sg * 8;
    const int awr_h = sp * A_PIPE_SZ + srow * 256 + (sg >> 2) * 128 +
                      (((sg & 3)    ) ^ (srow & 7)) * 16;
    const int awr_m = sp * A_PIPE_SZ + srow * 256 + (sg >> 2) * 128 +
                      (((sg & 3) | 4) ^ (srow & 7)) * 16;

    // ---- A fragment read offsets (pipe kp) ----
    const int ah_ch = ((lq    ) ^ (lr & 7)) * 16;
    const int am_ch = ((lq | 4) ^ (lr & 7)) * 16;
    const char* const ard = smem + kp * A_PIPE_SZ;

    // ---- B fragment base: global substep s = kp*64 + 2t + ks ----
    const _Float16* const wtB =
        wt + (size_t)(kp * 64) * 8192 + (wl * 16 + lr) * 32 + lq * 8;

    f32x4 acc[4];
#pragma unroll
    for (int i = 0; i < 4; i++) acc[i] = (f32x4)0.0f;

#define CONV_WRITE(a0, a1, buf)                                               \
    {                                                                         \
        half8 h, m;                                                           \
        _Pragma("unroll") for (int j = 0; j < 4; j++) {                       \
            _Float16 hh = (_Float16)a0[j];                                    \
            h[j] = hh; m[j] = (_Float16)(a0[j] - (float)hh);                  \
            hh = (_Float16)a1[j];                                             \
            h[4 + j] = hh; m[4 + j] = (_Float16)(a1[j] - (float)hh);          \
        }                                                                     \
        char* const wb = smem + (buf) * A_BUF_SZ;                             \
        *reinterpret_cast<half8*>(wb + awr_h) = h;                            \
        *reinterpret_cast<half8*>(wb + awr_m) = m;                            \
    }

#define BAR()                                                                 \
    asm volatile("s_waitcnt lgkmcnt(0)" ::: "memory");                        \
    __builtin_amdgcn_sched_barrier(0);                                        \
    __builtin_amdgcn_s_barrier();                                             \
    __builtin_amdgcn_sched_barrier(0);

#define LOADB(Bh0, Bm0, Bh1, Bm1, t)                                          \
    {                                                                         \
        const _Float16* bp0 = wtB + (size_t)((2 * (t)    ) & 63) * 8192;      \
        const _Float16* bp1 = wtB + (size_t)((2 * (t) + 1) & 63) * 8192;      \
        Bh0 = *reinterpret_cast<const half8*>(bp0);                           \
        Bm0 = *reinterpret_cast<const half8*>(bp0 + 4096);                    \
        Bh1 = *reinterpret_cast<const half8*>(bp1);                           \
        Bm1 = *reinterpret_cast<const half8*>(bp1 + 4096);                    \
    }

#define SUBSTEP(cur, ks, Bh, Bm)                                              \
    {                                                                         \
        half8 Ah[4], Am[4];                                                   \
        _Pragma("unroll") for (int rf = 0; rf < 4; rf++) {                    \
            const char* ab = ard + (cur) * A_BUF_SZ +                         \
                             (rf * 16 + lr) * 256 + (ks) * 128;               \
            Ah[rf] = *reinterpret_cast<const half8*>(ab + ah_ch);             \
            Am[rf] = *reinterpret_cast<const half8*>(ab + am_ch);             \
        }                                                                     \
        _Pragma("unroll") for (int rf = 0; rf < 4; rf++) {                    \
            acc[rf] = __builtin_amdgcn_mfma_f32_16x16x32_f16(                 \
                Am[rf], Bh, acc[rf], 0, 0, 0);                                \
            acc[rf] = __builtin_amdgcn_mfma_f32_16x16x32_f16(                 \
                Ah[rf], Bm, acc[rf], 0, 0, 0);                                \
            acc[rf] = __builtin_amdgcn_mfma_f32_16x16x32_f16(                 \
                Ah[rf], Bh, acc[rf], 0, 0, 0);                                \
        }                                                                     \
    }

// Pipe-0 macro-step (R16 order): B(t) first, A(t+2), MFMA, stage, barrier.
#define STEP0(cur, t, AC0, AC1, AN0, AN1)                                     \
    {                                                                         \
        half8 Bh0, Bm0, Bh1, Bm1;                                             \
        LOADB(Bh0, Bm0, Bh1, Bm1, t);                                         \
        __builtin_amdgcn_sched_barrier(0);                                    \
        const int kn = (((t) + 2) & (NT - 1)) * 64;                           \
        AN0 = *reinterpret_cast<const f32x4*>(xA + kn);                       \
        AN1 = *reinterpret_cast<const f32x4*>(xA + kn + 4);                   \
        __builtin_amdgcn_sched_barrier(0);                                    \
        SUBSTEP(cur, 0, Bh0, Bm0);                                            \
        SUBSTEP(cur, 1, Bh1, Bm1);                                            \
        CONV_WRITE(AC0, AC1, (cur) ^ 1);                                      \
        BAR();                                                                \
    }

// Pipe-1 macro-step (anti-phase): MFMA with pre-loaded B(t) first, then
// B(t+1) loads, then A(t+2) loads, stage, barrier.
#define STEP1(cur, t, UBh0, UBm0, UBh1, UBm1, NBh0, NBm0, NBh1, NBm1,         \
              AC0, AC1, AN0, AN1)                                             \
    {                                                                         \
        SUBSTEP(cur, 0, UBh0, UBm0);                                          \
        SUBSTEP(cur, 1, UBh1, UBm1);                                          \
        __builtin_amdgcn_sched_barrier(0);                                    \
        LOADB(NBh0, NBm0, NBh1, NBm1, (t) + 1);                               \
        __builtin_amdgcn_sched_barrier(0);                                    \
        const int kn = (((t) + 2) & (NT - 1)) * 64;                           \
        AN0 = *reinterpret_cast<const f32x4*>(xA + kn);                       \
        AN1 = *reinterpret_cast<const f32x4*>(xA + kn + 4);                   \
        __builtin_amdgcn_sched_barrier(0);                                    \
        CONV_WRITE(AC0, AC1, (cur) ^ 1);                                      \
        BAR();                                                                \
    }

    f32x4 aA0, aA1, aB0, aB1;
    half8 PBh0, PBm0, PBh1, PBm1, QBh0, QBm0, QBh1, QBm1;

    // ---- prologue: A(0) -> buf0; A(1) -> regs; pipe1: B(0) -> P set ----
    {
        const f32x4 a00 = *reinterpret_cast<const f32x4*>(xA);
        const f32x4 a01 = *reinterpret_cast<const f32x4*>(xA + 4);
        aA0 = *reinterpret_cast<const f32x4*>(xA + 64);
        aA1 = *reinterpret_cast<const f32x4*>(xA + 68);
        if (kp == 1) { LOADB(PBh0, PBm0, PBh1, PBm1, 0); }
        CONV_WRITE(a00, a01, 0);
        BAR();
    }

    // ---- main loop: 32 macro-steps, 2 per iteration (static indices) ----
    if (kp == 0) {
        for (int t = 0; t < NT; t += 2) {
            STEP0(0, t,     aA0, aA1, aB0, aB1);
            STEP0(1, t + 1, aB0, aB1, aA0, aA1);
        }
    } else {
        for (int t = 0; t < NT; t += 2) {
            STEP1(0, t,     PBh0, PBm0, PBh1, PBm1, QBh0, QBm0, QBh1, QBm1,
                  aA0, aA1, aB0, aB1);
            STEP1(1, t + 1, QBh0, QBm0, QBh1, QBm1, PBh0, PBm0, PBh1, PBm1,
                  aB0, aB1, aA0, aA1);
        }
    }

#undef STEP0
#undef STEP1
#undef SUBSTEP
#undef LOADB
#undef BAR
#undef CONV_WRITE

    // ---- merge the two K-pipes into lg (aliases A smem), scale by 1/64 ----
    float* lg = reinterpret_cast<float*>(smem);   // [64][129] = 33 KB
    if (kp == 1) {
#pragma unroll
        for (int rf = 0; rf < 4; rf++)
#pragma unroll
            for (int r = 0; r < 4; r++)
                lg[(rf * 16 + lq * 4 + r) * 129 + wl * 16 + lr] =
                    acc[rf][r] * 0.015625f;
    }
    __syncthreads();
    if (kp == 0) {
#pragma unroll
        for (int rf = 0; rf < 4; rf++)
#pragma unroll
            for (int r = 0; r < 4; r++)
                lg[(rf * 16 + lq * 4 + r) * 129 + wl * 16 + lr] +=
                    acc[rf][r] * 0.015625f;
    }
    __syncthreads();

    // ---- gate epilogue ----
    float* sm1v  = reinterpret_cast<float*>(smem + 40960);  // [64]
    float* sinvv = reinterpret_cast<float*>(smem + 41472);  // [64]

    if (tid < BM) {
        const int r = tid;
        const int t = row0 + r;
        float m1 = -1e30f, m2 = -1e30f;
        int   i1 = 0, i2 = 0;
        for (int e = 0; e < E_EXP; e++) {
            const float v = lg[r * 129 + e];
            if (v > m1)      { m2 = m1; i2 = i1; m1 = v; i1 = e; }
            else if (v > m2) { m2 = v; i2 = e; }
        }
        float s = 0.0f;
        for (int e = 0; e < E_EXP; e++) s += __expf(lg[r * 129 + e] - m1);
        const float inv = 1.0f / s;

        out[3 + 0 * T_TOK + t] = (float)i1;
        out[3 + 1 * T_TOK + t] = (float)i2;
        out[3 + 4 * T_TOK + t] = inv;
        out[3 + 5 * T_TOK + t] = __expf(m2 - m1) * inv;
        atomicAdd(&cnt1[i1], 1);
        sm1v[r]  = m1;
        sinvv[r] = inv;
    }
    __syncthreads();

    // parallel exp rewrite: 1024 threads x 8 cells (64 rows x 128 experts)
    {
        const int r  = tid >> 4;          // 0..63
        const int e0 = (tid & 15) * 8;    // 0..120
        const float m1 = sm1v[r], inv = sinvv[r];
#pragma unroll
        for (int j = 0; j < 8; j++)
            lg[r * 129 + e0 + j] = __expf(lg[r * 129 + e0 + j] - m1) * inv;
    }
    __syncthreads();

    if (tid < E_EXP) {
        float s = 0.0f;
        for (int r = 0; r < BM; r++) s += lg[r * 129 + tid];
        atomicAdd(&me[tid], s);
    }
}

// ---------------------------------------------------------------------------
// Kernel B: per-expert rank. 256 blocks x 1024 thr: blocks 0-127 scan idx1;
// blocks 128-255 scan idx2 starting at base = cnt1[e] (from gemm histogram).
// ---------------------------------------------------------------------------
__global__ __launch_bounds__(1024) void rank_kernel(
    float* __restrict__ out, const int* __restrict__ cnt1)
{
    const int  e      = blockIdx.x & 127;
    const bool second = blockIdx.x >= 128;
    const int  tid    = threadIdx.x;
    const int  lane   = tid & 63;
    const int  w      = tid >> 6;   // 0..15

    __shared__ int wtot[16];

    const float* idxA = out + 3 + (second ? T_TOK : 0);
    float* loc = out + 3 + (second ? 3 * T_TOK : 2 * T_TOK);

    const unsigned long long below = (1ull << lane) - 1ull;
    int base = second ? cnt1[e] : 0;

    for (int t0 = 0; t0 < T_TOK; t0 += 1024) {
        const int t = t0 + tid;
        const int f = ((int)idxA[t] == e);
        const unsigned long long m = __ballot(f);
        const int pre = __popcll(m & below);
        const int tot = __popcll(m);
        if (lane == 0) wtot[w] = tot;
        __syncthreads();
        int off = 0, all = 0;
#pragma unroll
        for (int i = 0; i < 16; i++) {
            const int v = wtot[i];
            if (i < w) off += v;
            all += v;
        }
        if (f) {
            const int rank = base + off + pre;
            loc[t] = (rank < CAP) ? (float)rank : 0.0f;
        }
        base += all;
        __syncthreads();
    }
}

// ---------------------------------------------------------------------------
// Kernel C: l_aux = sum(me * min(cnt1,CAP)) * E/(T*T); plus constants.
// ---------------------------------------------------------------------------
__global__ __launch_bounds__(128) void finalize_kernel(
    const float* __restrict__ me, const int* __restrict__ cnt1,
    float* __restrict__ out)
{
    __shared__ float red[2];
    const int tid = threadIdx.x;
    const int c = cnt1[tid];
    float p = me[tid] * (float)((c < CAP) ? c : CAP);
#pragma unroll
    for (int o = 32; o > 0; o >>= 1) p += __shfl_down(p, o);
    if ((tid & 63) == 0) red[tid >> 6] = p;
    __syncthreads();
    if (tid == 0) {
        const float tot = red[0] + red[1];
        out[0] = tot * ((float)E_EXP / ((float)T_TOK * (float)T_TOK));
        out[1] = (float)CAP;
        out[2] = (float)E_EXP;
    }
}

extern "C" void kernel_launch(void* const* d_in, const int* in_sizes, int n_in,
                              void* d_out, int out_size, void* d_ws, size_t ws_size,
                              hipStream_t stream)
{
    const float* x  = (const float*)d_in[0];
    const float* wg = (const float*)d_in[1];
    float* out = (float*)d_out;

    float* me   = (float*)d_ws;                      // 128 floats
    int*   cnt1 = (int*)((char*)d_ws + 512);         // 128 ints
    _Float16* wt = (_Float16*)((char*)d_ws + 1024);  // 2 MB K-tiled planes

    hipMemsetAsync(d_ws, 0, 1024, stream);
    prep_wt<<<256, 256, 0, stream>>>(wg, wt);
    gemm_gate<<<T_TOK / BM, 1024, 0, stream>>>(x, wt, out, me, cnt1);
    rank_kernel<<<2 * E_EXP, 1024, 0, stream>>>(out, cnt1);
    finalize_kernel<<<1, 128, 0, stream>>>(me, cnt1, out);
}

// Round 18
// 104.731 us; speedup vs baseline: 1.3799x; 1.0029x over previous
//
#include <hip/hip_runtime.h>

typedef _Float16 half8 __attribute__((ext_vector_type(8)));
typedef _Float16 half4 __attribute__((ext_vector_type(4)));
typedef float    f32x4 __attribute__((ext_vector_type(4)));

#define T_TOK 16384
#define D_DIM 4096
#define E_EXP 128
#define CAP   256
#define BM    64
#define NT    32   // macro K-steps per pipe, BK=64 each (K per pipe = 2048)

// A LDS: [pipe][buf][row 0..63][256 B]. Per row: 2 ks-blocks of 128 B (k=32).
// Within each 128B block: 8 chunks of 16B; h at chunk (g ^ (row&7)), m at
// ((g|4) ^ (row&7)), g = k-group 0..3. Write phases 2-way aliased (free),
// read phases conflict-free (R10/R11-verified layout).
#define A_BUF_SZ  16384
#define A_PIPE_SZ 32768

// ---------------------------------------------------------------------------
// Kernel 0: wg (fp32) -> K-step-tiled split-fp16 planes, scaled by 64.
// Substep s (k=32) block: h plane 8192 B | m plane 8192 B; expert e at e*64 B.
// ---------------------------------------------------------------------------
__global__ __launch_bounds__(256) void prep_wt(
    const float* __restrict__ wg, _Float16* __restrict__ wt)
{
    const int t = blockIdx.x * 256 + threadIdx.x;  // 65536 threads
    const int c = t & 3;
    const int e = (t >> 2) & 127;
    const int s = t >> 9;

    const float* src = wg + (size_t)e * D_DIM + s * 32 + c * 8;
    const f32x4 v0 = *reinterpret_cast<const f32x4*>(src);
    const f32x4 v1 = *reinterpret_cast<const f32x4*>(src + 4);

    half8 h, m;
#pragma unroll
    for (int j = 0; j < 4; j++) {
        float sv = v0[j] * 64.0f;
        _Float16 hh = (_Float16)sv;
        h[j] = hh; m[j] = (_Float16)(sv - (float)hh);
        sv = v1[j] * 64.0f;
        hh = (_Float16)sv;
        h[4 + j] = hh; m[4 + j] = (_Float16)(sv - (float)hh);
    }
    _Float16* dst = wt + (size_t)s * 8192 + e * 32 + c * 8;
    *reinterpret_cast<half8*>(dst)        = h;
    *reinterpret_cast<half8*>(dst + 4096) = m;
}

// ---------------------------------------------------------------------------
// Kernel A: R17 anti-phase K-pipes + T5 setprio around MFMA clusters.
// 1024 thr = 16 waves = 2 K-pipes x 8 expert-groups. Pipe 0 per step:
// B(t) loads -> A(t+2) loads -> MFMA -> stage A(t+1) -> lgkm-barrier.
// Pipe 1: MFMA (B pre-loaded, ping-pong P/Q) -> B(t+1) -> A(t+2) -> stage
// -> barrier. Role-split gives the CU scheduler arbitrage; setprio(1) lets
// MFMA-phase waves win issue slots against load-phase waves (T5 regime).
// ---------------------------------------------------------------------------
__global__ __launch_bounds__(1024, 4) void gemm_gate(
    const float* __restrict__ x, const _Float16* __restrict__ wt,
    float* __restrict__ out, float* __restrict__ me, int* __restrict__ cnt1)
{
    __shared__ char smem[2 * A_PIPE_SZ];   // 64 KB A tiles; logits alias after

    const int tid  = threadIdx.x;
    const int row0 = blockIdx.x * BM;
    const int lane = tid & 63;
    const int w    = tid >> 6;
    const int kp   = w >> 3;     // K-pipe 0/1
    const int wl   = w & 7;      // expert group: experts wl*16 .. +16
    const int lr   = lane & 15;
    const int lq   = lane >> 4;

    // ---- A staging role: threads 0-511 stage pipe 0, 512-1023 pipe 1 ----
    const int sp   = tid >> 9;
    const int srow = (tid >> 3) & 63;
    const int sg   = tid & 7;
    const float* xA = x + (size_t)(row0 + srow) * D_DIM + sp * 2048 + sg * 8;
    const int awr_h = sp * A_PIPE_SZ + srow * 256 + (sg >> 2) * 128 +
                      (((sg & 3)    ) ^ (srow & 7)) * 16;
    const int awr_m = sp * A_PIPE_SZ + srow * 256 + (sg >> 2) * 128 +
                      (((sg & 3) | 4) ^ (srow & 7)) * 16;

    // ---- A fragment read offsets (pipe kp) ----
    const int ah_ch = ((lq    ) ^ (lr & 7)) * 16;
    const int am_ch = ((lq | 4) ^ (lr & 7)) * 16;
    const char* const ard = smem + kp * A_PIPE_SZ;

    // ---- B fragment base: global substep s = kp*64 + 2t + ks ----
    const _Float16* const wtB =
        wt + (size_t)(kp * 64) * 8192 + (wl * 16 + lr) * 32 + lq * 8;

    f32x4 acc[4];
#pragma unroll
    for (int i = 0; i < 4; i++) acc[i] = (f32x4)0.0f;

#define CONV_WRITE(a0, a1, buf)                                               \
    {                                                                         \
        half8 h, m;                                                           \
        _Pragma("unroll") for (int j = 0; j < 4; j++) {                       \
            _Float16 hh = (_Float16)a0[j];                                    \
            h[j] = hh; m[j] = (_Float16)(a0[j] - (float)hh);                  \
            hh = (_Float16)a1[j];                                             \
            h[4 + j] = hh; m[4 + j] = (_Float16)(a1[j] - (float)hh);          \
        }                                                                     \
        char* const wb = smem + (buf) * A_BUF_SZ;                             \
        *reinterpret_cast<half8*>(wb + awr_h) = h;                            \
        *reinterpret_cast<half8*>(wb + awr_m) = m;                            \
    }

#define BAR()                                                                 \
    asm volatile("s_waitcnt lgkmcnt(0)" ::: "memory");                        \
    __builtin_amdgcn_sched_barrier(0);                                        \
    __builtin_amdgcn_s_barrier();                                             \
    __builtin_amdgcn_sched_barrier(0);

#define LOADB(Bh0, Bm0, Bh1, Bm1, t)                                          \
    {                                                                         \
        const _Float16* bp0 = wtB + (size_t)((2 * (t)    ) & 63) * 8192;      \
        const _Float16* bp1 = wtB + (size_t)((2 * (t) + 1) & 63) * 8192;      \
        Bh0 = *reinterpret_cast<const half8*>(bp0);                           \
        Bm0 = *reinterpret_cast<const half8*>(bp0 + 4096);                    \
        Bh1 = *reinterpret_cast<const half8*>(bp1);                           \
        Bm1 = *reinterpret_cast<const half8*>(bp1 + 4096);                    \
    }

#define SUBSTEP(cur, ks, Bh, Bm)                                              \
    {                                                                         \
        half8 Ah[4], Am[4];                                                   \
        _Pragma("unroll") for (int rf = 0; rf < 4; rf++) {                    \
            const char* ab = ard + (cur) * A_BUF_SZ +                         \
                             (rf * 16 + lr) * 256 + (ks) * 128;               \
            Ah[rf] = *reinterpret_cast<const half8*>(ab + ah_ch);             \
            Am[rf] = *reinterpret_cast<const half8*>(ab + am_ch);             \
        }                                                                     \
        __builtin_amdgcn_s_setprio(1);                                        \
        _Pragma("unroll") for (int rf = 0; rf < 4; rf++) {                    \
            acc[rf] = __builtin_amdgcn_mfma_f32_16x16x32_f16(                 \
                Am[rf], Bh, acc[rf], 0, 0, 0);                                \
            acc[rf] = __builtin_amdgcn_mfma_f32_16x16x32_f16(                 \
                Ah[rf], Bm, acc[rf], 0, 0, 0);                                \
            acc[rf] = __builtin_amdgcn_mfma_f32_16x16x32_f16(                 \
                Ah[rf], Bh, acc[rf], 0, 0, 0);                                \
        }                                                                     \
        __builtin_amdgcn_s_setprio(0);                                        \
    }

// Pipe-0 macro-step (R16 order): B(t) first, A(t+2), MFMA, stage, barrier.
#define STEP0(cur, t, AC0, AC1, AN0, AN1)                                     \
    {                                                                         \
        half8 Bh0, Bm0, Bh1, Bm1;                                             \
        LOADB(Bh0, Bm0, Bh1, Bm1, t);                                         \
        __builtin_amdgcn_sched_barrier(0);                                    \
        const int kn = (((t) + 2) & (NT - 1)) * 64;                           \
        AN0 = *reinterpret_cast<const f32x4*>(xA + kn);                       \
        AN1 = *reinterpret_cast<const f32x4*>(xA + kn + 4);                   \
        __builtin_amdgcn_sched_barrier(0);                                    \
        SUBSTEP(cur, 0, Bh0, Bm0);                                            \
        SUBSTEP(cur, 1, Bh1, Bm1);                                            \
        CONV_WRITE(AC0, AC1, (cur) ^ 1);                                      \
        BAR();                                                                \
    }

// Pipe-1 macro-step (anti-phase): MFMA with pre-loaded B(t) first, then
// B(t+1) loads, then A(t+2) loads, stage, barrier.
#define STEP1(cur, t, UBh0, UBm0, UBh1, UBm1, NBh0, NBm0, NBh1, NBm1,         \
              AC0, AC1, AN0, AN1)                                             \
    {                                                                         \
        SUBSTEP(cur, 0, UBh0, UBm0);                                          \
        SUBSTEP(cur, 1, UBh1, UBm1);                                          \
        __builtin_amdgcn_sched_barrier(0);                                    \
        LOADB(NBh0, NBm0, NBh1, NBm1, (t) + 1);                               \
        __builtin_amdgcn_sched_barrier(0);                                    \
        const int kn = (((t) + 2) & (NT - 1)) * 64;                           \
        AN0 = *reinterpret_cast<const f32x4*>(xA + kn);                       \
        AN1 = *reinterpret_cast<const f32x4*>(xA + kn + 4);                   \
        __builtin_amdgcn_sched_barrier(0);                                    \
        CONV_WRITE(AC0, AC1, (cur) ^ 1);                                      \
        BAR();                                                                \
    }

    f32x4 aA0, aA1, aB0, aB1;
    half8 PBh0, PBm0, PBh1, PBm1, QBh0, QBm0, QBh1, QBm1;

    // ---- prologue: A(0) -> buf0; A(1) -> regs; pipe1: B(0) -> P set ----
    {
        const f32x4 a00 = *reinterpret_cast<const f32x4*>(xA);
        const f32x4 a01 = *reinterpret_cast<const f32x4*>(xA + 4);
        aA0 = *reinterpret_cast<const f32x4*>(xA + 64);
        aA1 = *reinterpret_cast<const f32x4*>(xA + 68);
        if (kp == 1) { LOADB(PBh0, PBm0, PBh1, PBm1, 0); }
        CONV_WRITE(a00, a01, 0);
        BAR();
    }

    // ---- main loop: 32 macro-steps, 2 per iteration (static indices) ----
    if (kp == 0) {
        for (int t = 0; t < NT; t += 2) {
            STEP0(0, t,     aA0, aA1, aB0, aB1);
            STEP0(1, t + 1, aB0, aB1, aA0, aA1);
        }
    } else {
        for (int t = 0; t < NT; t += 2) {
            STEP1(0, t,     PBh0, PBm0, PBh1, PBm1, QBh0, QBm0, QBh1, QBm1,
                  aA0, aA1, aB0, aB1);
            STEP1(1, t + 1, QBh0, QBm0, QBh1, QBm1, PBh0, PBm0, PBh1, PBm1,
                  aB0, aB1, aA0, aA1);
        }
    }

#undef STEP0
#undef STEP1
#undef SUBSTEP
#undef LOADB
#undef BAR
#undef CONV_WRITE

    // ---- merge the two K-pipes into lg (aliases A smem), scale by 1/64 ----
    float* lg = reinterpret_cast<float*>(smem);   // [64][129] = 33 KB
    if (kp == 1) {
#pragma unroll
        for (int rf = 0; rf < 4; rf++)
#pragma unroll
            for (int r = 0; r < 4; r++)
                lg[(rf * 16 + lq * 4 + r) * 129 + wl * 16 + lr] =
                    acc[rf][r] * 0.015625f;
    }
    __syncthreads();
    if (kp == 0) {
#pragma unroll
        for (int rf = 0; rf < 4; rf++)
#pragma unroll
            for (int r = 0; r < 4; r++)
                lg[(rf * 16 + lq * 4 + r) * 129 + wl * 16 + lr] +=
                    acc[rf][r] * 0.015625f;
    }
    __syncthreads();

    // ---- gate epilogue ----
    float* sm1v  = reinterpret_cast<float*>(smem + 40960);  // [64]
    float* sinvv = reinterpret_cast<float*>(smem + 41472);  // [64]

    if (tid < BM) {
        const int r = tid;
        const int t = row0 + r;
        float m1 = -1e30f, m2 = -1e30f;
        int   i1 = 0, i2 = 0;
        for (int e = 0; e < E_EXP; e++) {
            const float v = lg[r * 129 + e];
            if (v > m1)      { m2 = m1; i2 = i1; m1 = v; i1 = e; }
            else if (v > m2) { m2 = v; i2 = e; }
        }
        float s = 0.0f;
        for (int e = 0; e < E_EXP; e++) s += __expf(lg[r * 129 + e] - m1);
        const float inv = 1.0f / s;

        out[3 + 0 * T_TOK + t] = (float)i1;
        out[3 + 1 * T_TOK + t] = (float)i2;
        out[3 + 4 * T_TOK + t] = inv;
        out[3 + 5 * T_TOK + t] = __expf(m2 - m1) * inv;
        atomicAdd(&cnt1[i1], 1);
        sm1v[r]  = m1;
        sinvv[r] = inv;
    }
    __syncthreads();

    // parallel exp rewrite: 1024 threads x 8 cells (64 rows x 128 experts)
    {
        const int r  = tid >> 4;          // 0..63
        const int e0 = (tid & 15) * 8;    // 0..120
        const float m1 = sm1v[r], inv = sinvv[r];
#pragma unroll
        for (int j = 0; j < 8; j++)
            lg[r * 129 + e0 + j] = __expf(lg[r * 129 + e0 + j] - m1) * inv;
    }
    __syncthreads();

    if (tid < E_EXP) {
        float s = 0.0f;
        for (int r = 0; r < BM; r++) s += lg[r * 129 + tid];
        atomicAdd(&me[tid], s);
    }
}

// ---------------------------------------------------------------------------
// Kernel B: per-expert rank. 256 blocks x 1024 thr: blocks 0-127 scan idx1;
// blocks 128-255 scan idx2 starting at base = cnt1[e] (from gemm histogram).
// ---------------------------------------------------------------------------
__global__ __launch_bounds__(1024) void rank_kernel(
    float* __restrict__ out, const int* __restrict__ cnt1)
{
    const int  e      = blockIdx.x & 127;
    const bool second = blockIdx.x >= 128;
    const int  tid    = threadIdx.x;
    const int  lane   = tid & 63;
    const int  w      = tid >> 6;   // 0..15

    __shared__ int wtot[16];

    const float* idxA = out + 3 + (second ? T_TOK : 0);
    float* loc = out + 3 + (second ? 3 * T_TOK : 2 * T_TOK);

    const unsigned long long below = (1ull << lane) - 1ull;
    int base = second ? cnt1[e] : 0;

    for (int t0 = 0; t0 < T_TOK; t0 += 1024) {
        const int t = t0 + tid;
        const int f = ((int)idxA[t] == e);
        const unsigned long long m = __ballot(f);
        const int pre = __popcll(m & below);
        const int tot = __popcll(m);
        if (lane == 0) wtot[w] = tot;
        __syncthreads();
        int off = 0, all = 0;
#pragma unroll
        for (int i = 0; i < 16; i++) {
            const int v = wtot[i];
            if (i < w) off += v;
            all += v;
        }
        if (f) {
            const int rank = base + off + pre;
            loc[t] = (rank < CAP) ? (float)rank : 0.0f;
        }
        base += all;
        __syncthreads();
    }
}

// ---------------------------------------------------------------------------
// Kernel C: l_aux = sum(me * min(cnt1,CAP)) * E/(T*T); plus constants.
// ---------------------------------------------------------------------------
__global__ __launch_bounds__(128) void finalize_kernel(
    const float* __restrict__ me, const int* __restrict__ cnt1,
    float* __restrict__ out)
{
    __shared__ float red[2];
    const int tid = threadIdx.x;
    const int c = cnt1[tid];
    float p = me[tid] * (float)((c < CAP) ? c : CAP);
#pragma unroll
    for (int o = 32; o > 0; o >>= 1) p += __shfl_down(p, o);
    if ((tid & 63) == 0) red[tid >> 6] = p;
    __syncthreads();
    if (tid == 0) {
        const float tot = red[0] + red[1];
        out[0] = tot * ((float)E_EXP / ((float)T_TOK * (float)T_TOK));
        out[1] = (float)CAP;
        out[2] = (float)E_EXP;
    }
}

extern "C" void kernel_launch(void* const* d_in, const int* in_sizes, int n_in,
                              void* d_out, int out_size, void* d_ws, size_t ws_size,
                              hipStream_t stream)
{
    const float* x  = (const float*)d_in[0];
    const float* wg = (const float*)d_in[1];
    float* out = (float*)d_out;

    float* me   = (float*)d_ws;                      // 128 floats
    int*   cnt1 = (int*)((char*)d_ws + 512);         // 128 ints
    _Float16* wt = (_Float16*)((char*)d_ws + 1024);  // 2 MB K-tiled planes

    hipMemsetAsync(d_ws, 0, 1024, stream);
    prep_wt<<<256, 256, 0, stream>>>(wg, wt);
    gemm_gate<<<T_TOK / BM, 1024, 0, stream>>>(x, wt, out, me, cnt1);
    rank_kernel<<<2 * E_EXP, 1024, 0, stream>>>(out, cnt1);
    finalize_kernel<<<1, 128, 0, stream>>>(me, cnt1, out);
}